// Round 2
// baseline (717.926 us; speedup 1.0000x reference)
//
#include <hip/hip_runtime.h>
#include <hip/hip_bf16.h>
#include <math.h>

#define EPSQ 1e-5f
#define NPART 64

// ---------------- weight quantization ----------------

// Pass 1: per-block partial sums of w and |w| in double.
__global__ __launch_bounds__(256) void wpartial(const float* __restrict__ w, int n,
                                                double* __restrict__ p) {
    __shared__ double ls[4], la[4];
    int t = threadIdx.x;
    double s = 0.0, a = 0.0;
    for (int i = blockIdx.x * blockDim.x + t; i < n; i += gridDim.x * blockDim.x) {
        double v = (double)w[i];
        s += v; a += fabs(v);
    }
    for (int o = 32; o; o >>= 1) { s += __shfl_down(s, o); a += __shfl_down(a, o); }
    int wid = t >> 6;
    if ((t & 63) == 0) { ls[wid] = s; la[wid] = a; }
    __syncthreads();
    if (t == 0) {
        for (int i = 1; i < (int)(blockDim.x >> 6); i++) { s += ls[i]; a += la[i]; }
        p[blockIdx.x * 2] = s; p[blockIdx.x * 2 + 1] = a;
    }
}

// Pass 2a: binary quantize  sign(w - mean(w)) * mean(|w|)
__global__ __launch_bounds__(256) void wq_bin_k(const float* __restrict__ w,
                                                float* __restrict__ out, int n,
                                                const double* __restrict__ p) {
    __shared__ float smean, sscale;
    if (threadIdx.x == 0) {
        double s = 0.0, a = 0.0;
        for (int i = 0; i < NPART; i++) { s += p[2 * i]; a += p[2 * i + 1]; }
        smean = (float)(s / n); sscale = (float)(a / n);
    }
    __syncthreads();
    float mean = smean, sc = sscale;
    for (int i = blockIdx.x * blockDim.x + threadIdx.x; i < n; i += gridDim.x * blockDim.x) {
        float d = w[i] - mean;
        out[i] = d > 0.f ? sc : (d < 0.f ? -sc : 0.f);
    }
}

// Pass 2b: 4-bit symmetric quantize  (clip(round(w*s-0.5),-8,7)+0.5)/s, s=2/mean(|w|)
__global__ __launch_bounds__(256) void wq_4bit_k(const float* __restrict__ w,
                                                 float* __restrict__ out, int n,
                                                 const double* __restrict__ p) {
    __shared__ float sscale;
    if (threadIdx.x == 0) {
        double a = 0.0;
        for (int i = 0; i < NPART; i++) a += p[2 * i + 1];
        float mag = fmaxf((float)(a / n), EPSQ);
        sscale = 2.0f / mag;   // QUANTSCALE*8 = 2.0
    }
    __syncthreads();
    float sc = sscale;
    for (int i = blockIdx.x * blockDim.x + threadIdx.x; i < n; i += gridDim.x * blockDim.x) {
        float q = fminf(fmaxf(rintf(w[i] * sc - 0.5f), -8.f), 7.f) + 0.5f;
        out[i] = q / sc;
    }
}

// ---------------- fused conv stack (one block per image) ----------------
// x[B,1,16,16] -> act_quant rows of 16 -> conv1 3x3 (16ch) + relu [16,14,14]
// -> act_quant rows of 14 -> depthwise 3x3 + relu [16,12,12]
// -> act_quant rows of 12 -> grouped 12x12 conv (96 out) + relu [96]
// -> rmsnorm + act_quant over 96 -> xq96[B,96]
__global__ __launch_bounds__(256) void conv_fused(
    const float* __restrict__ x, const float* __restrict__ w1,
    const float* __restrict__ w1b, const float* __restrict__ w2,
    float* __restrict__ xq96) {
    __shared__ float sx[256];
    __shared__ float sh1[16 * 14 * 14];
    __shared__ float sh2[16 * 12 * 12];
    __shared__ float ssc[224];
    __shared__ float sw1[144], sw1b[144];
    __shared__ float sh3[96];
    __shared__ float srs[2];
    int b = blockIdx.x, t = threadIdx.x;

    sx[t] = x[b * 256 + t];
    if (t < 144) { sw1[t] = w1[t]; sw1b[t] = w1b[t]; }
    __syncthreads();

    // act_quant input: 16 rows of 16
    if (t < 16) {
        float m = 0.f;
        for (int j = 0; j < 16; j++) m = fmaxf(m, fabsf(sx[t * 16 + j]));
        ssc[t] = 127.0f / fmaxf(m, EPSQ);
    }
    __syncthreads();
    {
        float s = ssc[t >> 4];
        sx[t] = fminf(fmaxf(rintf(sx[t] * s), -128.f), 127.f) / s;
    }
    __syncthreads();

    // conv1 3x3, 1->16 ch, + relu
    for (int idx = t; idx < 16 * 14 * 14; idx += 256) {
        int c = idx / 196, rem = idx % 196, r = rem / 14, q = rem % 14;
        const float* wk = &sw1[c * 9];
        float acc = 0.f;
        #pragma unroll
        for (int i = 0; i < 3; i++)
            #pragma unroll
            for (int j = 0; j < 3; j++)
                acc += sx[(r + i) * 16 + (q + j)] * wk[i * 3 + j];
        sh1[idx] = fmaxf(acc, 0.f);
    }
    __syncthreads();

    // act_quant: 224 rows of 14
    if (t < 224) {
        float m = 0.f;
        for (int j = 0; j < 14; j++) m = fmaxf(m, fabsf(sh1[t * 14 + j]));
        ssc[t] = 127.0f / fmaxf(m, EPSQ);
    }
    __syncthreads();
    for (int idx = t; idx < 3136; idx += 256) {
        float s = ssc[idx / 14];
        sh1[idx] = fminf(fmaxf(rintf(sh1[idx] * s), -128.f), 127.f) / s;
    }
    __syncthreads();

    // depthwise conv1b 3x3 + relu
    for (int idx = t; idx < 16 * 12 * 12; idx += 256) {
        int c = idx / 144, rem = idx % 144, r = rem / 12, q = rem % 12;
        const float* wk = &sw1b[c * 9];
        const float* base = &sh1[c * 196];
        float acc = 0.f;
        #pragma unroll
        for (int i = 0; i < 3; i++)
            #pragma unroll
            for (int j = 0; j < 3; j++)
                acc += base[(r + i) * 14 + (q + j)] * wk[i * 3 + j];
        sh2[idx] = fmaxf(acc, 0.f);
    }
    __syncthreads();

    // act_quant: 192 rows of 12
    if (t < 192) {
        float m = 0.f;
        for (int j = 0; j < 12; j++) m = fmaxf(m, fabsf(sh2[t * 12 + j]));
        ssc[t] = 127.0f / fmaxf(m, EPSQ);
    }
    __syncthreads();
    for (int idx = t; idx < 2304; idx += 256) {
        float s = ssc[idx / 12];
        sh2[idx] = fminf(fmaxf(rintf(sh2[idx] * s), -128.f), 127.f) / s;
    }
    __syncthreads();

    // grouped conv2: 96 outputs, each = dot(sh2[group], w2[o]) over 144, + relu
    if (t < 96) {
        int g = t / 6;
        const float* base = &sh2[g * 144];
        const float* wk = &w2[t * 144];
        float acc = 0.f;
        for (int i = 0; i < 144; i++) acc += base[i] * wk[i];
        sh3[t] = fmaxf(acc, 0.f);
    }
    __syncthreads();

    // rmsnorm + act_quant over the 96-vector
    if (t < 64) {
        float a = sh3[t];
        float bv = (t < 32) ? sh3[64 + t] : 0.f;
        float ss = a * a + bv * bv;
        float mx = fmaxf(fabsf(a), fabsf(bv));
        for (int o = 32; o; o >>= 1) {
            ss += __shfl_down(ss, o);
            mx = fmaxf(mx, __shfl_down(mx, o));
        }
        if (t == 0) {
            float r = 1.0f / sqrtf(ss / 96.0f + 1e-5f);
            float s = 127.0f / fmaxf(r * mx, EPSQ);
            srs[0] = r; srs[1] = s;
        }
    }
    __syncthreads();
    if (t < 96) {
        float r = srs[0], s = srs[1];
        float xn = sh3[t] * r;
        xq96[(size_t)b * 96 + t] = fminf(fmaxf(rintf(xn * s), -128.f), 127.f) / s;
    }
}

// ---------------- rmsnorm + act_quant for D=512 rows ----------------
__global__ __launch_bounds__(256) void rmsq512(const float* __restrict__ in,
                                               float* __restrict__ out) {
    __shared__ float wsum[4], wmax[4], fr[2];
    int b = blockIdx.x, t = threadIdx.x;
    const float* xr = in + (size_t)b * 512;
    float v0 = xr[t], v1 = xr[t + 256];
    float ss = v0 * v0 + v1 * v1;
    float mx = fmaxf(fabsf(v0), fabsf(v1));
    for (int o = 32; o; o >>= 1) {
        ss += __shfl_down(ss, o);
        mx = fmaxf(mx, __shfl_down(mx, o));
    }
    int wid = t >> 6;
    if ((t & 63) == 0) { wsum[wid] = ss; wmax[wid] = mx; }
    __syncthreads();
    if (t == 0) {
        float S = wsum[0] + wsum[1] + wsum[2] + wsum[3];
        float M = fmaxf(fmaxf(wmax[0], wmax[1]), fmaxf(wmax[2], wmax[3]));
        float r = 1.0f / sqrtf(S / 512.0f + 1e-5f);
        float s = 127.0f / fmaxf(r * M, EPSQ);
        fr[0] = r; fr[1] = s;
    }
    __syncthreads();
    float r = fr[0], s = fr[1];
    out[(size_t)b * 512 + t]       = fminf(fmaxf(rintf(v0 * r * s), -128.f), 127.f) / s;
    out[(size_t)b * 512 + t + 256] = fminf(fmaxf(rintf(v1 * r * s), -128.f), 127.f) / s;
}

// ---------------- fp32 tiled GEMM:  C[M,N] = relu?(X[M,K] @ W[N,K]^T) ----------------
// BM=BN=128, BK=8, 256 threads, 8x8 micro-tile. K % 8 == 0, M % 128 == 0. N guarded.
__global__ __launch_bounds__(256) void gemm_bit(const float* __restrict__ X,
                                                const float* __restrict__ W,
                                                float* __restrict__ C,
                                                int N, int K, int dorelu) {
    __shared__ float Xs[8][128];
    __shared__ float Ws[8][128];
    int tid = threadIdx.x;
    int row0 = blockIdx.y * 128, col0 = blockIdx.x * 128;
    int lr = tid >> 1;
    int lk = (tid & 1) * 4;
    const float* Xg = X + (size_t)(row0 + lr) * K + lk;
    int wrow = col0 + lr;
    const float* Wg = W + (size_t)wrow * K + lk;
    int tx = tid & 15, ty = tid >> 4;
    float acc[8][8] = {};
    for (int k0 = 0; k0 < K; k0 += 8) {
        float4 xv = *(const float4*)(Xg + k0);
        float4 wv = make_float4(0.f, 0.f, 0.f, 0.f);
        if (wrow < N) wv = *(const float4*)(Wg + k0);
        Xs[lk + 0][lr] = xv.x; Xs[lk + 1][lr] = xv.y;
        Xs[lk + 2][lr] = xv.z; Xs[lk + 3][lr] = xv.w;
        Ws[lk + 0][lr] = wv.x; Ws[lk + 1][lr] = wv.y;
        Ws[lk + 2][lr] = wv.z; Ws[lk + 3][lr] = wv.w;
        __syncthreads();
        #pragma unroll
        for (int kk = 0; kk < 8; kk++) {
            float a[8], bb[8];
            *(float4*)&a[0]  = *(const float4*)&Xs[kk][ty * 8];
            *(float4*)&a[4]  = *(const float4*)&Xs[kk][ty * 8 + 4];
            *(float4*)&bb[0] = *(const float4*)&Ws[kk][tx * 8];
            *(float4*)&bb[4] = *(const float4*)&Ws[kk][tx * 8 + 4];
            #pragma unroll
            for (int i = 0; i < 8; i++)
                #pragma unroll
                for (int j = 0; j < 8; j++)
                    acc[i][j] += a[i] * bb[j];
        }
        __syncthreads();
    }
    #pragma unroll
    for (int i = 0; i < 8; i++) {
        int r = row0 + ty * 8 + i;
        #pragma unroll
        for (int j = 0; j < 8; j++) {
            int c = col0 + tx * 8 + j;
            if (c < N) {
                float v = acc[i][j];
                if (dorelu) v = fmaxf(v, 0.f);
                C[(size_t)r * N + c] = v;
            }
        }
    }
}

// ---------------- launcher ----------------
extern "C" void kernel_launch(void* const* d_in, const int* in_sizes, int n_in,
                              void* d_out, int out_size, void* d_ws, size_t ws_size,
                              hipStream_t stream) {
    const float* x      = (const float*)d_in[0];
    const float* w_c1   = (const float*)d_in[1];
    const float* w_c1b  = (const float*)d_in[2];
    const float* w_c2   = (const float*)d_in[3];
    const float* w_fc1  = (const float*)d_in[4];
    const float* w_fc2  = (const float*)d_in[5];
    const float* w_fc3  = (const float*)d_in[6];
    const float* w_fcl  = (const float*)d_in[7];
    float* out = (float*)d_out;
    float* ws  = (float*)d_ws;
    const int B = 16384;

    // ws layout (floats)
    float* c1q  = ws + 0;        // 144
    float* c1bq = ws + 144;      // 144
    float* c2q  = ws + 288;      // 13824
    float* f1q  = ws + 14112;    // 49152
    float* f2q  = ws + 63264;    // 262144
    float* f3q  = ws + 325408;   // 262144
    float* flq  = ws + 587552;   // 5120  -> end 592672
    double* part = (double*)(ws + 592672);   // 64*2 doubles = 256 floats
    float* xq96  = ws + 592928;              // B*96
    float* xq512 = xq96 + (size_t)B * 96;    // B*512
    float* hA    = xq512 + (size_t)B * 512;  // B*512
    // total: 592928 + 96B + 512B + 512B floats ~ 76 MB

    // --- quantize weights ---
    wpartial<<<NPART, 256, 0, stream>>>(w_c1, 144, part);
    wq_4bit_k<<<1, 256, 0, stream>>>(w_c1, c1q, 144, part);
    wpartial<<<NPART, 256, 0, stream>>>(w_c1b, 144, part);
    wq_4bit_k<<<1, 256, 0, stream>>>(w_c1b, c1bq, 144, part);
    wpartial<<<NPART, 256, 0, stream>>>(w_c2, 13824, part);
    wq_4bit_k<<<14, 256, 0, stream>>>(w_c2, c2q, 13824, part);

    wpartial<<<NPART, 256, 0, stream>>>(w_fc1, 49152, part);
    wq_bin_k<<<48, 256, 0, stream>>>(w_fc1, f1q, 49152, part);
    wpartial<<<NPART, 256, 0, stream>>>(w_fc2, 262144, part);
    wq_bin_k<<<256, 256, 0, stream>>>(w_fc2, f2q, 262144, part);
    wpartial<<<NPART, 256, 0, stream>>>(w_fc3, 262144, part);
    wq_bin_k<<<256, 256, 0, stream>>>(w_fc3, f3q, 262144, part);
    wpartial<<<NPART, 256, 0, stream>>>(w_fcl, 5120, part);
    wq_bin_k<<<5, 256, 0, stream>>>(w_fcl, flq, 5120, part);

    // --- conv stack (writes rms+quantized 96-vec) ---
    conv_fused<<<B, 256, 0, stream>>>(x, c1q, c1bq, c2q, xq96);

    // --- fc1: [B,96] @ [512,96]^T -> hA, relu ---
    {
        dim3 g(4, B / 128);
        gemm_bit<<<g, 256, 0, stream>>>(xq96, f1q, hA, 512, 96, 1);
    }
    rmsq512<<<B, 256, 0, stream>>>(hA, xq512);
    // --- fc2 ---
    {
        dim3 g(4, B / 128);
        gemm_bit<<<g, 256, 0, stream>>>(xq512, f2q, hA, 512, 512, 1);
    }
    rmsq512<<<B, 256, 0, stream>>>(hA, xq512);
    // --- fc3 ---
    {
        dim3 g(4, B / 128);
        gemm_bit<<<g, 256, 0, stream>>>(xq512, f3q, hA, 512, 512, 1);
    }
    rmsq512<<<B, 256, 0, stream>>>(hA, xq512);
    // --- fcl: [B,512] @ [10,512]^T -> out, no relu ---
    {
        dim3 g(1, B / 128);
        gemm_bit<<<g, 256, 0, stream>>>(xq512, flq, out, 10, 512, 0);
    }
}

// Round 6
// 369.792 us; speedup vs baseline: 1.9414x; 1.9414x over previous
//
#include <hip/hip_runtime.h>
#include <math.h>

#define EPSQ 1e-5

typedef int v4i  __attribute__((ext_vector_type(4)));
typedef int v16i __attribute__((ext_vector_type(16)));

// ================= weight stats: one block per tensor, f64 =================
__device__ void block_stat(const float* __restrict__ w, int n, double2* outp) {
    __shared__ double ls[4], la[4];
    int t = threadIdx.x;
    double s = 0.0, a = 0.0;
    int nv = n >> 2;
    const float4* w4 = (const float4*)w;
    for (int i = t; i < nv; i += 256) {
        float4 v = w4[i];
        s += (double)v.x + (double)v.y + (double)v.z + (double)v.w;
        a += fabs((double)v.x) + fabs((double)v.y) + fabs((double)v.z) + fabs((double)v.w);
    }
    for (int o = 32; o; o >>= 1) { s += __shfl_down(s, o); a += __shfl_down(a, o); }
    if ((t & 63) == 0) { ls[t >> 6] = s; la[t >> 6] = a; }
    __syncthreads();
    if (t == 0) {
        for (int i = 1; i < 4; i++) { s += ls[i]; a += la[i]; }
        outp->x = s / n; outp->y = a / n;
    }
}

__global__ __launch_bounds__(256) void wstats(
    const float* __restrict__ a0, const float* __restrict__ a1,
    const float* __restrict__ a2, const float* __restrict__ a3,
    const float* __restrict__ a4, const float* __restrict__ a5,
    const float* __restrict__ a6, double2* __restrict__ stats) {
    switch (blockIdx.x) {
        case 0: block_stat(a0, 144,    stats + 0); break;
        case 1: block_stat(a1, 144,    stats + 1); break;
        case 2: block_stat(a2, 13824,  stats + 2); break;
        case 3: block_stat(a3, 49152,  stats + 3); break;
        case 4: block_stat(a4, 262144, stats + 4); break;
        case 5: block_stat(a5, 262144, stats + 5); break;
        case 6: block_stat(a6, 5120,   stats + 6); break;
    }
}

// ============ conv weights -> ODD integer levels (as f32 ints) ============
// wq value = odd * (mag/4), odd = 2*clip(rint(w*sc-0.5),-8,7)+1, sc = 2/max(mag,eps)
__device__ inline float q4odd(float w, double mag) {
    double sc = 2.0 / fmax(mag, EPSQ);
    double q = fmin(fmax(rint((double)w * sc - 0.5), -8.0), 7.0);
    return (float)(2.0 * q + 1.0);
}

__global__ __launch_bounds__(256) void wq_conv(
    const float* __restrict__ wc1, const float* __restrict__ wc1b,
    const float* __restrict__ wc2, const double2* __restrict__ stats,
    float* __restrict__ c1o, float* __restrict__ c1bo, float* __restrict__ c2o) {
    int i = blockIdx.x * 256 + threadIdx.x;
    if (i < 144) c1o[i] = q4odd(wc1[i], stats[0].y);
    else if (i < 288) c1bo[i - 144] = q4odd(wc1b[i - 144], stats[1].y);
    else if (i < 288 + 13824) { int j = i - 288; c2o[j] = q4odd(wc2[j], stats[2].y); }
}

// ============ fc weights: binary sign {-1,0,1} as int8 (f64 mean) ============
__device__ inline char bsign(float w, double mean) {
    double d = (double)w - mean;
    return d > 0.0 ? (char)1 : (d < 0.0 ? (char)-1 : (char)0);
}

__global__ __launch_bounds__(256) void wq_fc(
    const float* __restrict__ wfc1, const float* __restrict__ wfc2,
    const float* __restrict__ wfc3, const float* __restrict__ wfcl,
    const double2* __restrict__ stats,
    char* __restrict__ f1, char* __restrict__ f2,
    char* __restrict__ f3, char* __restrict__ fl) {
    int i = blockIdx.x * 256 + threadIdx.x;
    if (i < 65536) {                       // f1: [512][128] padded, K=96
        int row = i >> 7, k = i & 127;
        f1[i] = (k < 96) ? bsign(wfc1[row * 96 + k], stats[3].x) : (char)0;
        return;
    }
    i -= 65536;
    if (i < 262144) { f2[i] = bsign(wfc2[i], stats[4].x); return; }
    i -= 262144;
    if (i < 262144) { f3[i] = bsign(wfc3[i], stats[5].x); return; }
    i -= 262144;
    if (i < 5120)   { fl[i] = bsign(wfcl[i], stats[6].x); }
}

// ============ exact integer 3-row pixel dot, f64 scale combine ============
template <int Wd>
__device__ inline double cpix(const float (&rq)[3][Wd], const float* wv,
                              const double* inv, int qx) {
    // products <= 127*15, sums <= 5715 < 2^24  -> fp32 arithmetic is EXACT
    float d0 = rq[0][qx] * wv[0] + rq[0][qx + 1] * wv[1] + rq[0][qx + 2] * wv[2];
    float d1 = rq[1][qx] * wv[3] + rq[1][qx + 1] * wv[4] + rq[1][qx + 2] * wv[5];
    float d2 = rq[2][qx] * wv[6] + rq[2][qx + 1] * wv[7] + rq[2][qx + 2] * wv[8];
    return (double)d0 * inv[0] + (double)d1 * inv[1] + (double)d2 * inv[2];
}

// ================= fused conv stack: one block per image =================
// All activations carried as exact integer levels (f32-ints) + per-row f64
// inverse scales. All rounding decisions in f64.
__global__ __launch_bounds__(256) void conv_fused(
    const float* __restrict__ x, const float* __restrict__ w1o,
    const float* __restrict__ w1bo, const float* __restrict__ w2o,
    const double2* __restrict__ stats,
    char* __restrict__ xq96, double* __restrict__ arow) {
    __shared__ float sxp[16][17];
    __shared__ double sinv0[16];
    __shared__ float sh1[16][14][15];
    __shared__ double sinv1[16][14];
    __shared__ float sh2[16][12][13];
    __shared__ double sinv2[16][12];
    __shared__ float sw1[144], sw1b[144];
    __shared__ double sh3[96];
    __shared__ double srs[2];
    int b = blockIdx.x, t = threadIdx.x;
    double cw1  = fmax(stats[0].y, EPSQ) * 0.25;
    double cw1b = fmax(stats[1].y, EPSQ) * 0.25;
    double cw2  = fmax(stats[2].y, EPSQ) * 0.25;

    // --- load + act_quant input (per row of 16) ---
    float v = x[(size_t)b * 256 + t];
    if (t < 144) { sw1[t] = w1o[t]; sw1b[t] = w1bo[t]; }
    float m = fabsf(v);
    for (int o = 8; o; o >>= 1) m = fmaxf(m, __shfl_xor(m, o));
    double s0 = 127.0 / fmax((double)m, EPSQ);
    sxp[t >> 4][t & 15] = (float)fmin(fmax(rint((double)v * s0), -128.0), 127.0);
    if ((t & 15) == 0) sinv0[t >> 4] = 1.0 / s0;
    __syncthreads();

    // --- conv1 3x3, 1->16ch, relu, act_quant rows of 14 (two-pass, exact) ---
    if (t < 224) {
        int c = t / 14, r = t % 14;
        float rq[3][16]; double inv[3];
        #pragma unroll
        for (int i = 0; i < 3; i++) {
            inv[i] = sinv0[r + i];
            #pragma unroll
            for (int j = 0; j < 16; j++) rq[i][j] = sxp[r + i][j];
        }
        float wv[9];
        #pragma unroll
        for (int k = 0; k < 9; k++) wv[k] = sw1[c * 9 + k];
        double mx = 0.0;
        #pragma unroll
        for (int qx = 0; qx < 14; qx++)
            mx = fmax(mx, fmax(cpix(rq, wv, inv, qx) * cw1, 0.0));
        double s2 = 127.0 / fmax(mx, EPSQ);
        sinv1[c][r] = 1.0 / s2;
        #pragma unroll
        for (int qx = 0; qx < 14; qx++) {
            double val = fmax(cpix(rq, wv, inv, qx) * cw1, 0.0);
            sh1[c][r][qx] = (float)fmin(fmax(rint(val * s2), -128.0), 127.0);
        }
    }
    __syncthreads();

    // --- depthwise 3x3, relu, act_quant rows of 12 ---
    if (t < 192) {
        int c = t / 12, r = t % 12;
        float rq[3][14]; double inv[3];
        #pragma unroll
        for (int i = 0; i < 3; i++) {
            inv[i] = sinv1[c][r + i];
            #pragma unroll
            for (int j = 0; j < 14; j++) rq[i][j] = sh1[c][r + i][j];
        }
        float wv[9];
        #pragma unroll
        for (int k = 0; k < 9; k++) wv[k] = sw1b[c * 9 + k];
        double mx = 0.0;
        #pragma unroll
        for (int qx = 0; qx < 12; qx++)
            mx = fmax(mx, fmax(cpix(rq, wv, inv, qx) * cw1b, 0.0));
        double s3 = 127.0 / fmax(mx, EPSQ);
        sinv2[c][r] = 1.0 / s3;
        #pragma unroll
        for (int qx = 0; qx < 12; qx++) {
            double val = fmax(cpix(rq, wv, inv, qx) * cw1b, 0.0);
            sh2[c][r][qx] = (float)fmin(fmax(rint(val * s3), -128.0), 127.0);
        }
    }
    __syncthreads();

    // --- grouped conv2: 96 outputs, 12 exact int row-dots each, f64 combine ---
    if (t < 96) {
        int g = t / 6;
        const float* wk = w2o + t * 144;
        double acc = 0.0;
        #pragma unroll 4
        for (int hh = 0; hh < 12; hh++) {
            float d = 0.f;
            #pragma unroll
            for (int ww = 0; ww < 12; ww++) d += sh2[g][hh][ww] * wk[hh * 12 + ww];
            acc += (double)d * sinv2[g][hh];
        }
        sh3[t] = fmax(acc * cw2, 0.0);
    }
    __syncthreads();

    // --- rmsnorm + act_quant over 96, f64 ---
    if (t < 64) {
        double a = sh3[t];
        double bb = (t < 32) ? sh3[64 + t] : 0.0;
        double ss = a * a + bb * bb;
        double mxx = fmax(fabs(a), fabs(bb));
        for (int o = 32; o; o >>= 1) {
            ss += __shfl_down(ss, o);
            mxx = fmax(mxx, __shfl_down(mxx, o));
        }
        if (t == 0) {
            double r = 1.0 / sqrt(ss / 96.0 + 1e-5);
            double s4 = 127.0 / fmax(mxx * r, EPSQ);
            srs[0] = r; srs[1] = s4;
        }
    }
    __syncthreads();
    if (t < 128) {
        char q = 0;
        if (t < 96) {
            double xn = sh3[t] * srs[0];
            q = (char)(int)fmin(fmax(rint(xn * srs[1]), -128.0), 127.0);
        }
        xq96[(size_t)b * 128 + t] = q;
        if (t == 0) arow[b] = 1.0 / srs[1];
    }
}

// ========== int8 MFMA GEMM: h_int32 = relu?(Xq · Wq^T)  (exact) ==========
__global__ __launch_bounds__(256) void gemm_i8(
    const char* __restrict__ Xq, const char* __restrict__ Wq,
    int* __restrict__ h, int N, int K, int dorelu) {
    __shared__ char As[16384];
    __shared__ char Bs[16384];
    int t = threadIdx.x;
    int lane = t & 63;
    int w = t >> 6, wr = w >> 1, wc = w & 1;
    int m0 = blockIdx.y * 128, n0 = blockIdx.x * 128;

    v16i acc[2][2] = {};

    for (int k0 = 0; k0 < K; k0 += 128) {
        #pragma unroll
        for (int p = 0; p < 4; p++) {
            int slot = p * 256 + t;
            int row = slot >> 3;
            int cb = (slot & 7) * 16;
            int4 va = *(const int4*)(Xq + (size_t)(m0 + row) * K + k0 + cb);
            int4 vb = *(const int4*)(Wq + (size_t)(n0 + row) * K + k0 + cb);
            int dst = row * 128 + (cb ^ ((row & 7) << 4));
            *(int4*)(As + dst) = va;
            *(int4*)(Bs + dst) = vb;
        }
        __syncthreads();
        int ra0 = wr * 64 + (lane & 31);
        int rb0 = wc * 64 + (lane & 31);
        int ksel = (lane >> 5) * 16;
        #pragma unroll
        for (int kk = 0; kk < 4; kk++) {
            int kb = kk * 32 + ksel;
            v4i a0 = *(v4i*)(As + ra0 * 128        + (kb ^ ((ra0 & 7) << 4)));
            v4i a1 = *(v4i*)(As + (ra0 + 32) * 128 + (kb ^ ((ra0 & 7) << 4)));
            v4i b0 = *(v4i*)(Bs + rb0 * 128        + (kb ^ ((rb0 & 7) << 4)));
            v4i b1 = *(v4i*)(Bs + (rb0 + 32) * 128 + (kb ^ ((rb0 & 7) << 4)));
            acc[0][0] = __builtin_amdgcn_mfma_i32_32x32x32_i8(a0, b0, acc[0][0], 0, 0, 0);
            acc[0][1] = __builtin_amdgcn_mfma_i32_32x32x32_i8(a0, b1, acc[0][1], 0, 0, 0);
            acc[1][0] = __builtin_amdgcn_mfma_i32_32x32x32_i8(a1, b0, acc[1][0], 0, 0, 0);
            acc[1][1] = __builtin_amdgcn_mfma_i32_32x32x32_i8(a1, b1, acc[1][1], 0, 0, 0);
        }
        __syncthreads();
    }

    // C/D layout: col = lane&31, row = (reg&3) + 8*(reg>>2) + 4*(lane>>5)
    #pragma unroll
    for (int mt = 0; mt < 2; mt++) {
        int rbase = m0 + wr * 64 + mt * 32 + 4 * (lane >> 5);
        #pragma unroll
        for (int nt = 0; nt < 2; nt++) {
            int cbase = n0 + wc * 64 + nt * 32 + (lane & 31);
            #pragma unroll
            for (int g = 0; g < 4; g++)
                #pragma unroll
                for (int q = 0; q < 4; q++) {
                    int vv = acc[mt][nt][g * 4 + q];
                    if (dorelu) vv = max(vv, 0);      // exact relu (scales > 0)
                    h[(size_t)(rbase + g * 8 + q) * N + cbase] = vv;
                }
        }
    }
}

// ====== rmsnorm + act_quant from raw int32 h + f64 scale (exact chain) ======
__global__ __launch_bounds__(256) void rmsq_i8(const int* __restrict__ h,
                                               const double2* __restrict__ stats,
                                               int sidx,
                                               double* __restrict__ arow,
                                               char* __restrict__ xq) {
    __shared__ double wsumd[4];
    __shared__ int wmaxi[4];
    __shared__ double fr[2];
    int b = blockIdx.x, t = threadIdx.x;
    const int* xr = h + (size_t)b * 512;
    int v0 = xr[t], v1 = xr[t + 256];
    double ss = (double)v0 * (double)v0 + (double)v1 * (double)v1;
    int mi = max(abs(v0), abs(v1));
    for (int o = 32; o; o >>= 1) {
        ss += __shfl_down(ss, o);
        mi = max(mi, __shfl_down(mi, o));
    }
    if ((t & 63) == 0) { wsumd[t >> 6] = ss; wmaxi[t >> 6] = mi; }
    __syncthreads();
    if (t == 0) {
        double S = wsumd[0] + wsumd[1] + wsumd[2] + wsumd[3];
        int M = max(max(wmaxi[0], wmaxi[1]), max(wmaxi[2], wmaxi[3]));
        double c = stats[sidx].y * arow[b];     // value_j = c * int_j, exact
        double mean = S * c * c / 512.0;
        double r = 1.0 / sqrt(mean + 1e-5);
        double s = 127.0 / fmax((double)M * c * r, EPSQ);
        fr[0] = c * r * s;
        fr[1] = s;
    }
    __syncthreads();
    double cs = fr[0];
    char q0 = (char)(int)fmin(fmax(rint((double)v0 * cs), -128.0), 127.0);
    char q1 = (char)(int)fmin(fmax(rint((double)v1 * cs), -128.0), 127.0);
    xq[(size_t)b * 512 + t] = q0;
    xq[(size_t)b * 512 + t + 256] = q1;
    if (t == 0) arow[b] = 1.0 / fr[1];
}

// ================= final layer: N=10, exact int dot =================
__device__ inline int bdot(int a, int b) {
    int r = ((a << 24) >> 24) * ((b << 24) >> 24);
    r += ((a << 16) >> 24) * ((b << 16) >> 24);
    r += ((a << 8) >> 24) * ((b << 8) >> 24);
    r += (a >> 24) * (b >> 24);
    return r;
}

__global__ __launch_bounds__(256) void fcl_k(const char* __restrict__ Xq,
                                             const char* __restrict__ Wq,
                                             const double* __restrict__ arow,
                                             const double2* __restrict__ stats,
                                             float* __restrict__ out) {
    int gi = blockIdx.x * 256 + threadIdx.x;     // 163840 = 16384*10 exact
    int mrow = gi / 10, n = gi - mrow * 10;
    const int4* xp = (const int4*)(Xq + (size_t)mrow * 512);
    const int4* wp = (const int4*)(Wq + n * 512);
    int acc = 0;
    #pragma unroll 8
    for (int i = 0; i < 32; i++) {
        int4 a = xp[i], b = wp[i];
        acc += bdot(a.x, b.x) + bdot(a.y, b.y) + bdot(a.z, b.z) + bdot(a.w, b.w);
    }
    out[gi] = (float)((double)acc * stats[6].y * arow[mrow]);
}

// ================= launcher =================
extern "C" void kernel_launch(void* const* d_in, const int* in_sizes, int n_in,
                              void* d_out, int out_size, void* d_ws, size_t ws_size,
                              hipStream_t stream) {
    const float* x     = (const float*)d_in[0];
    const float* w_c1  = (const float*)d_in[1];
    const float* w_c1b = (const float*)d_in[2];
    const float* w_c2  = (const float*)d_in[3];
    const float* w_fc1 = (const float*)d_in[4];
    const float* w_fc2 = (const float*)d_in[5];
    const float* w_fc3 = (const float*)d_in[6];
    const float* w_fcl = (const float*)d_in[7];
    float* out = (float*)d_out;
    char* wsb = (char*)d_ws;
    const int B = 16384;

    // ws layout (byte offsets, 16B-aligned)
    float*   c1o   = (float*)(wsb + 0);          // 576 B
    float*   c1bo  = (float*)(wsb + 1024);       // 576 B
    float*   c2o   = (float*)(wsb + 2048);       // 55296 B
    double2* stats = (double2*)(wsb + 57344);    // 112 B
    char*    f1q   = wsb + 65536;                // 512*128
    char*    f2q   = wsb + 131072;               // 512*512
    char*    f3q   = wsb + 393216;               // 512*512
    char*    flq   = wsb + 655360;               // 10*512
    double*  arow  = (double*)(wsb + 663552);    // B doubles -> 794624
    char*    xq96  = wsb + 1048576;              // B*128
    char*    xq512 = wsb + 3145728;              // B*512
    int*     h     = (int*)(wsb + 11534336);     // B*512 int32 (end ~43 MB)

    // --- weight stats + quantization ---
    wstats<<<7, 256, 0, stream>>>(w_c1, w_c1b, w_c2, w_fc1, w_fc2, w_fc3, w_fcl, stats);
    wq_conv<<<56, 256, 0, stream>>>(w_c1, w_c1b, w_c2, stats, c1o, c1bo, c2o);
    wq_fc<<<2324, 256, 0, stream>>>(w_fc1, w_fc2, w_fc3, w_fcl, stats, f1q, f2q, f3q, flq);

    // --- conv stack -> int8 [B,128] + f64 arow ---
    conv_fused<<<B, 256, 0, stream>>>(x, c1o, c1bo, c2o, stats, xq96, arow);

    // --- fc1 (K=128 padded), raw int32 out ---
    gemm_i8<<<dim3(4, B / 128), 256, 0, stream>>>(xq96, f1q, h, 512, 128, 1);
    rmsq_i8<<<B, 256, 0, stream>>>(h, stats, 3, arow, xq512);
    // --- fc2 ---
    gemm_i8<<<dim3(4, B / 128), 256, 0, stream>>>(xq512, f2q, h, 512, 512, 1);
    rmsq_i8<<<B, 256, 0, stream>>>(h, stats, 4, arow, xq512);
    // --- fc3 ---
    gemm_i8<<<dim3(4, B / 128), 256, 0, stream>>>(xq512, f3q, h, 512, 512, 1);
    rmsq_i8<<<B, 256, 0, stream>>>(h, stats, 5, arow, xq512);
    // --- fcl ---
    fcl_k<<<640, 256, 0, stream>>>(xq512, flq, arow, stats, out);
}

// Round 7
// 292.206 us; speedup vs baseline: 2.4569x; 1.2655x over previous
//
#include <hip/hip_runtime.h>
#include <math.h>

#define EPSQ 1e-5

typedef int v4i  __attribute__((ext_vector_type(4)));
typedef int v16i __attribute__((ext_vector_type(16)));

// ================= weight stats: partial sums, f64 =================
// Writes {sum,asum} raw (divn==0) or {mean,amean} (divn>0).
__device__ void bstat(const float* __restrict__ w, int cnt, double2* dst, int divn) {
    __shared__ double ls[4], la[4];
    int t = threadIdx.x;
    double s = 0.0, a = 0.0;
    const float4* w4 = (const float4*)w;
    int nv = cnt >> 2;
    for (int i = t; i < nv; i += 256) {
        float4 v = w4[i];
        s += (double)v.x + (double)v.y + (double)v.z + (double)v.w;
        a += fabs((double)v.x) + fabs((double)v.y) + fabs((double)v.z) + fabs((double)v.w);
    }
    for (int o = 32; o; o >>= 1) { s += __shfl_down(s, o); a += __shfl_down(a, o); }
    if ((t & 63) == 0) { ls[t >> 6] = s; la[t >> 6] = a; }
    __syncthreads();
    if (t == 0) {
        for (int i = 1; i < 4; i++) { s += ls[i]; a += la[i]; }
        if (divn > 0) { dst->x = s / divn; dst->y = a / divn; }
        else          { dst->x = s;        dst->y = a; }
    }
}

// grid = 40 blocks: 0:c1 1:c1b 2:c2 3:fcl | 4-7:fc1/4 | 8-23:fc2/16 | 24-39:fc3/16
__global__ __launch_bounds__(256) void wstats_part(
    const float* __restrict__ a0, const float* __restrict__ a1,
    const float* __restrict__ a2, const float* __restrict__ a3,
    const float* __restrict__ a4, const float* __restrict__ a5,
    const float* __restrict__ a6, double2* __restrict__ part,
    double2* __restrict__ stats) {
    int b = blockIdx.x;
    if      (b == 0) bstat(a0, 144,   stats + 0, 144);
    else if (b == 1) bstat(a1, 144,   stats + 1, 144);
    else if (b == 2) bstat(a2, 13824, stats + 2, 13824);
    else if (b == 3) bstat(a6, 5120,  stats + 6, 5120);
    else if (b < 8)  bstat(a3 + (b - 4)  * 12288, 12288, part + (b - 4), 0);
    else if (b < 24) bstat(a4 + (b - 8)  * 16384, 16384, part + 4 + (b - 8), 0);
    else             bstat(a5 + (b - 24) * 16384, 16384, part + 20 + (b - 24), 0);
}

__global__ __launch_bounds__(64) void wstats_comb(const double2* __restrict__ part,
                                                  double2* __restrict__ stats) {
    int t = threadIdx.x;
    if (t == 0) {
        double s = 0, a = 0;
        for (int i = 0; i < 4; i++) { s += part[i].x; a += part[i].y; }
        stats[3].x = s / 49152.0; stats[3].y = a / 49152.0;
    } else if (t == 1) {
        double s = 0, a = 0;
        for (int i = 4; i < 20; i++) { s += part[i].x; a += part[i].y; }
        stats[4].x = s / 262144.0; stats[4].y = a / 262144.0;
    } else if (t == 2) {
        double s = 0, a = 0;
        for (int i = 20; i < 36; i++) { s += part[i].x; a += part[i].y; }
        stats[5].x = s / 262144.0; stats[5].y = a / 262144.0;
    }
}

// ============ conv weights -> ODD integer levels (as f32 ints) ============
__device__ inline float q4odd(float w, double mag) {
    double sc = 2.0 / fmax(mag, EPSQ);
    double q = fmin(fmax(rint((double)w * sc - 0.5), -8.0), 7.0);
    return (float)(2.0 * q + 1.0);
}

__global__ __launch_bounds__(256) void wq_conv(
    const float* __restrict__ wc1, const float* __restrict__ wc1b,
    const float* __restrict__ wc2, const double2* __restrict__ stats,
    float* __restrict__ c1o, float* __restrict__ c1bo, float* __restrict__ c2o) {
    int i = blockIdx.x * 256 + threadIdx.x;
    if (i < 144) c1o[i] = q4odd(wc1[i], stats[0].y);
    else if (i < 288) c1bo[i - 144] = q4odd(wc1b[i - 144], stats[1].y);
    else if (i < 288 + 13824) { int j = i - 288; c2o[j] = q4odd(wc2[j], stats[2].y); }
}

// ============ fc weights: binary sign {-1,0,1} as int8 (f64 mean) ============
__device__ inline char bsign(float w, double mean) {
    double d = (double)w - mean;
    return d > 0.0 ? (char)1 : (d < 0.0 ? (char)-1 : (char)0);
}

__global__ __launch_bounds__(256) void wq_fc(
    const float* __restrict__ wfc1, const float* __restrict__ wfc2,
    const float* __restrict__ wfc3, const float* __restrict__ wfcl,
    const double2* __restrict__ stats,
    char* __restrict__ f1, char* __restrict__ f2,
    char* __restrict__ f3, char* __restrict__ fl) {
    int i = blockIdx.x * 256 + threadIdx.x;
    if (i < 65536) {                       // f1: [512][128] padded, K=96
        int row = i >> 7, k = i & 127;
        f1[i] = (k < 96) ? bsign(wfc1[row * 96 + k], stats[3].x) : (char)0;
        return;
    }
    i -= 65536;
    if (i < 262144) { f2[i] = bsign(wfc2[i], stats[4].x); return; }
    i -= 262144;
    if (i < 262144) { f3[i] = bsign(wfc3[i], stats[5].x); return; }
    i -= 262144;
    if (i < 5120)   { fl[i] = bsign(wfcl[i], stats[6].x); }
}

// ============ exact integer 3-row pixel dot, f64 scale combine ============
template <int Wd>
__device__ inline double cpix(const float (&rq)[3][Wd], const float* wv,
                              const double* inv, int qx) {
    // products <= 127*15, sums <= 5715 < 2^24  -> fp32 arithmetic is EXACT
    float d0 = rq[0][qx] * wv[0] + rq[0][qx + 1] * wv[1] + rq[0][qx + 2] * wv[2];
    float d1 = rq[1][qx] * wv[3] + rq[1][qx + 1] * wv[4] + rq[1][qx + 2] * wv[5];
    float d2 = rq[2][qx] * wv[6] + rq[2][qx + 1] * wv[7] + rq[2][qx + 2] * wv[8];
    return (double)d0 * inv[0] + (double)d1 * inv[1] + (double)d2 * inv[2];
}

// ================= fused conv stack: one block per image =================
// v3: conv row outputs kept in f64 registers between max-pass and quant
// (no recompute); conv2 parallelized to 192 threads (2 half-sums/output).
__global__ __launch_bounds__(256) void conv_fused(
    const float* __restrict__ x, const float* __restrict__ w1o,
    const float* __restrict__ w1bo, const float* __restrict__ w2o,
    const double2* __restrict__ stats,
    char* __restrict__ xq96, double* __restrict__ arow) {
    __shared__ float sxp[16][17];
    __shared__ double sinv0[16];
    __shared__ float sh1[16][14][15];
    __shared__ double sinv1[16][14];
    __shared__ float sh2[16][12][13];
    __shared__ double sinv2[16][12];
    __shared__ float sw1[144], sw1b[144];
    __shared__ double sh3p[2][96];
    __shared__ double sh3[96];
    __shared__ double srs[2];
    int b = blockIdx.x, t = threadIdx.x;
    double cw1  = fmax(stats[0].y, EPSQ) * 0.25;
    double cw1b = fmax(stats[1].y, EPSQ) * 0.25;
    double cw2  = fmax(stats[2].y, EPSQ) * 0.25;

    // --- load + act_quant input (per row of 16) ---
    float v = x[(size_t)b * 256 + t];
    if (t < 144) { sw1[t] = w1o[t]; sw1b[t] = w1bo[t]; }
    float m = fabsf(v);
    for (int o = 8; o; o >>= 1) m = fmaxf(m, __shfl_xor(m, o));
    double s0 = 127.0 / fmax((double)m, EPSQ);
    sxp[t >> 4][t & 15] = (float)fmin(fmax(rint((double)v * s0), -128.0), 127.0);
    if ((t & 15) == 0) sinv0[t >> 4] = 1.0 / s0;
    __syncthreads();

    // --- conv1 3x3, 1->16ch, relu, act_quant rows of 14 (single pass) ---
    if (t < 224) {
        int c = t / 14, r = t % 14;
        float rq[3][16]; double inv[3];
        #pragma unroll
        for (int i = 0; i < 3; i++) {
            inv[i] = sinv0[r + i];
            #pragma unroll
            for (int j = 0; j < 16; j++) rq[i][j] = sxp[r + i][j];
        }
        float wv[9];
        #pragma unroll
        for (int k = 0; k < 9; k++) wv[k] = sw1[c * 9 + k];
        double vals[14]; double mx = 0.0;
        #pragma unroll
        for (int qx = 0; qx < 14; qx++) {
            vals[qx] = fmax(cpix(rq, wv, inv, qx) * cw1, 0.0);
            mx = fmax(mx, vals[qx]);
        }
        double s2 = 127.0 / fmax(mx, EPSQ);
        sinv1[c][r] = 1.0 / s2;
        #pragma unroll
        for (int qx = 0; qx < 14; qx++)
            sh1[c][r][qx] = (float)fmin(fmax(rint(vals[qx] * s2), -128.0), 127.0);
    }
    __syncthreads();

    // --- depthwise 3x3, relu, act_quant rows of 12 (single pass) ---
    if (t < 192) {
        int c = t / 12, r = t % 12;
        float rq[3][14]; double inv[3];
        #pragma unroll
        for (int i = 0; i < 3; i++) {
            inv[i] = sinv1[c][r + i];
            #pragma unroll
            for (int j = 0; j < 14; j++) rq[i][j] = sh1[c][r + i][j];
        }
        float wv[9];
        #pragma unroll
        for (int k = 0; k < 9; k++) wv[k] = sw1b[c * 9 + k];
        double vals[12]; double mx = 0.0;
        #pragma unroll
        for (int qx = 0; qx < 12; qx++) {
            vals[qx] = fmax(cpix(rq, wv, inv, qx) * cw1b, 0.0);
            mx = fmax(mx, vals[qx]);
        }
        double s3 = 127.0 / fmax(mx, EPSQ);
        sinv2[c][r] = 1.0 / s3;
        #pragma unroll
        for (int qx = 0; qx < 12; qx++)
            sh2[c][r][qx] = (float)fmin(fmax(rint(vals[qx] * s3), -128.0), 127.0);
    }
    __syncthreads();

    // --- grouped conv2: 192 threads, 2 half-partials per output ---
    if (t < 192) {
        int o = t % 96, half = t / 96;
        int g = o / 6;
        const float* wk = w2o + o * 144 + half * 72;
        double acc = 0.0;
        #pragma unroll
        for (int hh = 0; hh < 6; hh++) {
            int row = half * 6 + hh;
            float4 w0 = *(const float4*)(wk + hh * 12);
            float4 w1 = *(const float4*)(wk + hh * 12 + 4);
            float4 w2v = *(const float4*)(wk + hh * 12 + 8);
            const float* sr = &sh2[g][row][0];
            float d = 0.f;
            d += sr[0] * w0.x; d += sr[1] * w0.y; d += sr[2] * w0.z; d += sr[3] * w0.w;
            d += sr[4] * w1.x; d += sr[5] * w1.y; d += sr[6] * w1.z; d += sr[7] * w1.w;
            d += sr[8] * w2v.x; d += sr[9] * w2v.y; d += sr[10] * w2v.z; d += sr[11] * w2v.w;
            acc += (double)d * sinv2[g][row];
        }
        sh3p[half][o] = acc;
    }
    __syncthreads();
    if (t < 96) sh3[t] = fmax((sh3p[0][t] + sh3p[1][t]) * cw2, 0.0);
    __syncthreads();

    // --- rmsnorm + act_quant over 96, f64 ---
    if (t < 64) {
        double a = sh3[t];
        double bb = (t < 32) ? sh3[64 + t] : 0.0;
        double ss = a * a + bb * bb;
        double mxx = fmax(fabs(a), fabs(bb));
        for (int o = 32; o; o >>= 1) {
            ss += __shfl_down(ss, o);
            mxx = fmax(mxx, __shfl_down(mxx, o));
        }
        if (t == 0) {
            double r = 1.0 / sqrt(ss / 96.0 + 1e-5);
            double s4 = 127.0 / fmax(mxx * r, EPSQ);
            srs[0] = r; srs[1] = s4;
        }
    }
    __syncthreads();
    if (t < 128) {
        char q = 0;
        if (t < 96) {
            double xn = sh3[t] * srs[0];
            q = (char)(int)fmin(fmax(rint(xn * srs[1]), -128.0), 127.0);
        }
        xq96[(size_t)b * 128 + t] = q;
        if (t == 0) arow[b] = 1.0 / srs[1];
    }
}

// ========== int8 MFMA GEMM: h_int32 = relu?(Xq · Wq^T)  (exact) ==========
__global__ __launch_bounds__(256) void gemm_i8(
    const char* __restrict__ Xq, const char* __restrict__ Wq,
    int* __restrict__ h, int N, int K, int dorelu) {
    __shared__ char As[16384];
    __shared__ char Bs[16384];
    int t = threadIdx.x;
    int lane = t & 63;
    int w = t >> 6, wr = w >> 1, wc = w & 1;
    int m0 = blockIdx.y * 128, n0 = blockIdx.x * 128;

    v16i acc[2][2] = {};

    for (int k0 = 0; k0 < K; k0 += 128) {
        #pragma unroll
        for (int p = 0; p < 4; p++) {
            int slot = p * 256 + t;
            int row = slot >> 3;
            int cb = (slot & 7) * 16;
            int4 va = *(const int4*)(Xq + (size_t)(m0 + row) * K + k0 + cb);
            int4 vb = *(const int4*)(Wq + (size_t)(n0 + row) * K + k0 + cb);
            int dst = row * 128 + (cb ^ ((row & 7) << 4));
            *(int4*)(As + dst) = va;
            *(int4*)(Bs + dst) = vb;
        }
        __syncthreads();
        int ra0 = wr * 64 + (lane & 31);
        int rb0 = wc * 64 + (lane & 31);
        int ksel = (lane >> 5) * 16;
        #pragma unroll
        for (int kk = 0; kk < 4; kk++) {
            int kb = kk * 32 + ksel;
            v4i a0 = *(v4i*)(As + ra0 * 128        + (kb ^ ((ra0 & 7) << 4)));
            v4i a1 = *(v4i*)(As + (ra0 + 32) * 128 + (kb ^ ((ra0 & 7) << 4)));
            v4i b0 = *(v4i*)(Bs + rb0 * 128        + (kb ^ ((rb0 & 7) << 4)));
            v4i b1 = *(v4i*)(Bs + (rb0 + 32) * 128 + (kb ^ ((rb0 & 7) << 4)));
            acc[0][0] = __builtin_amdgcn_mfma_i32_32x32x32_i8(a0, b0, acc[0][0], 0, 0, 0);
            acc[0][1] = __builtin_amdgcn_mfma_i32_32x32x32_i8(a0, b1, acc[0][1], 0, 0, 0);
            acc[1][0] = __builtin_amdgcn_mfma_i32_32x32x32_i8(a1, b0, acc[1][0], 0, 0, 0);
            acc[1][1] = __builtin_amdgcn_mfma_i32_32x32x32_i8(a1, b1, acc[1][1], 0, 0, 0);
        }
        __syncthreads();
    }

    // C/D layout: col = lane&31, row = (reg&3) + 8*(reg>>2) + 4*(lane>>5)
    #pragma unroll
    for (int mt = 0; mt < 2; mt++) {
        int rbase = m0 + wr * 64 + mt * 32 + 4 * (lane >> 5);
        #pragma unroll
        for (int nt = 0; nt < 2; nt++) {
            int cbase = n0 + wc * 64 + nt * 32 + (lane & 31);
            #pragma unroll
            for (int g = 0; g < 4; g++)
                #pragma unroll
                for (int q = 0; q < 4; q++) {
                    int vv = acc[mt][nt][g * 4 + q];
                    if (dorelu) vv = max(vv, 0);      // exact relu (scales > 0)
                    h[(size_t)(rbase + g * 8 + q) * N + cbase] = vv;
                }
        }
    }
}

// ====== rmsnorm + act_quant from raw int32 h + f64 scale (exact chain) ======
__global__ __launch_bounds__(256) void rmsq_i8(const int* __restrict__ h,
                                               const double2* __restrict__ stats,
                                               int sidx,
                                               double* __restrict__ arow,
                                               char* __restrict__ xq) {
    __shared__ double wsumd[4];
    __shared__ int wmaxi[4];
    __shared__ double fr[2];
    int b = blockIdx.x, t = threadIdx.x;
    const int* xr = h + (size_t)b * 512;
    int v0 = xr[t], v1 = xr[t + 256];
    double ss = (double)v0 * (double)v0 + (double)v1 * (double)v1;
    int mi = max(abs(v0), abs(v1));
    for (int o = 32; o; o >>= 1) {
        ss += __shfl_down(ss, o);
        mi = max(mi, __shfl_down(mi, o));
    }
    if ((t & 63) == 0) { wsumd[t >> 6] = ss; wmaxi[t >> 6] = mi; }
    __syncthreads();
    if (t == 0) {
        double S = wsumd[0] + wsumd[1] + wsumd[2] + wsumd[3];
        int M = max(max(wmaxi[0], wmaxi[1]), max(wmaxi[2], wmaxi[3]));
        double c = stats[sidx].y * arow[b];     // value_j = c * int_j, exact
        double mean = S * c * c / 512.0;
        double r = 1.0 / sqrt(mean + 1e-5);
        double s = 127.0 / fmax((double)M * c * r, EPSQ);
        fr[0] = c * r * s;
        fr[1] = s;
    }
    __syncthreads();
    double cs = fr[0];
    char q0 = (char)(int)fmin(fmax(rint((double)v0 * cs), -128.0), 127.0);
    char q1 = (char)(int)fmin(fmax(rint((double)v1 * cs), -128.0), 127.0);
    xq[(size_t)b * 512 + t] = q0;
    xq[(size_t)b * 512 + t + 256] = q1;
    if (t == 0) arow[b] = 1.0 / fr[1];
}

// ================= final layer: N=10, exact int dot =================
__device__ inline int bdot(int a, int b) {
    int r = ((a << 24) >> 24) * ((b << 24) >> 24);
    r += ((a << 16) >> 24) * ((b << 16) >> 24);
    r += ((a << 8) >> 24) * ((b << 8) >> 24);
    r += (a >> 24) * (b >> 24);
    return r;
}

__global__ __launch_bounds__(256) void fcl_k(const char* __restrict__ Xq,
                                             const char* __restrict__ Wq,
                                             const double* __restrict__ arow,
                                             const double2* __restrict__ stats,
                                             float* __restrict__ out) {
    int gi = blockIdx.x * 256 + threadIdx.x;     // 163840 = 16384*10 exact
    int mrow = gi / 10, n = gi - mrow * 10;
    const int4* xp = (const int4*)(Xq + (size_t)mrow * 512);
    const int4* wp = (const int4*)(Wq + n * 512);
    int acc = 0;
    #pragma unroll 8
    for (int i = 0; i < 32; i++) {
        int4 a = xp[i], b = wp[i];
        acc += bdot(a.x, b.x) + bdot(a.y, b.y) + bdot(a.z, b.z) + bdot(a.w, b.w);
    }
    out[gi] = (float)((double)acc * stats[6].y * arow[mrow]);
}

// ================= launcher =================
extern "C" void kernel_launch(void* const* d_in, const int* in_sizes, int n_in,
                              void* d_out, int out_size, void* d_ws, size_t ws_size,
                              hipStream_t stream) {
    const float* x     = (const float*)d_in[0];
    const float* w_c1  = (const float*)d_in[1];
    const float* w_c1b = (const float*)d_in[2];
    const float* w_c2  = (const float*)d_in[3];
    const float* w_fc1 = (const float*)d_in[4];
    const float* w_fc2 = (const float*)d_in[5];
    const float* w_fc3 = (const float*)d_in[6];
    const float* w_fcl = (const float*)d_in[7];
    float* out = (float*)d_out;
    char* wsb = (char*)d_ws;
    const int B = 16384;

    // ws layout (byte offsets, 16B-aligned)
    float*   c1o   = (float*)(wsb + 0);          // 576 B
    float*   c1bo  = (float*)(wsb + 1024);       // 576 B
    float*   c2o   = (float*)(wsb + 2048);       // 55296 B
    double2* stats = (double2*)(wsb + 57344);    // 112 B
    double2* part  = (double2*)(wsb + 57856);    // 36*16 = 576 B
    char*    f1q   = wsb + 65536;                // 512*128
    char*    f2q   = wsb + 131072;               // 512*512
    char*    f3q   = wsb + 393216;               // 512*512
    char*    flq   = wsb + 655360;               // 10*512
    double*  arow  = (double*)(wsb + 663552);    // B doubles -> 794624
    char*    xq96  = wsb + 1048576;              // B*128
    char*    xq512 = wsb + 3145728;              // B*512
    int*     h     = (int*)(wsb + 11534336);     // B*512 int32 (end ~43 MB)

    // --- weight stats + quantization ---
    wstats_part<<<40, 256, 0, stream>>>(w_c1, w_c1b, w_c2, w_fc1, w_fc2, w_fc3,
                                        w_fcl, part, stats);
    wstats_comb<<<1, 64, 0, stream>>>(part, stats);
    wq_conv<<<56, 256, 0, stream>>>(w_c1, w_c1b, w_c2, stats, c1o, c1bo, c2o);
    wq_fc<<<2324, 256, 0, stream>>>(w_fc1, w_fc2, w_fc3, w_fcl, stats, f1q, f2q, f3q, flq);

    // --- conv stack -> int8 [B,128] + f64 arow ---
    conv_fused<<<B, 256, 0, stream>>>(x, c1o, c1bo, c2o, stats, xq96, arow);

    // --- fc1 (K=128 padded), raw int32 out ---
    gemm_i8<<<dim3(4, B / 128), 256, 0, stream>>>(xq96, f1q, h, 512, 128, 1);
    rmsq_i8<<<B, 256, 0, stream>>>(h, stats, 3, arow, xq512);
    // --- fc2 ---
    gemm_i8<<<dim3(4, B / 128), 256, 0, stream>>>(xq512, f2q, h, 512, 512, 1);
    rmsq_i8<<<B, 256, 0, stream>>>(h, stats, 4, arow, xq512);
    // --- fc3 ---
    gemm_i8<<<dim3(4, B / 128), 256, 0, stream>>>(xq512, f3q, h, 512, 512, 1);
    rmsq_i8<<<B, 256, 0, stream>>>(h, stats, 5, arow, xq512);
    // --- fcl ---
    fcl_k<<<640, 256, 0, stream>>>(xq512, flq, arow, stats, out);
}

// Round 8
// 247.336 us; speedup vs baseline: 2.9026x; 1.1814x over previous
//
#include <hip/hip_runtime.h>
#include <math.h>

#define EPSQ 1e-5

typedef int v4i  __attribute__((ext_vector_type(4)));
typedef int v16i __attribute__((ext_vector_type(16)));

// ================= weight stats: partial sums, f64 =================
__device__ void bstat(const float* __restrict__ w, int cnt, double2* dst, int divn) {
    __shared__ double ls[4], la[4];
    int t = threadIdx.x;
    double s = 0.0, a = 0.0;
    const float4* w4 = (const float4*)w;
    int nv = cnt >> 2;
    for (int i = t; i < nv; i += 256) {
        float4 v = w4[i];
        s += (double)v.x + (double)v.y + (double)v.z + (double)v.w;
        a += fabs((double)v.x) + fabs((double)v.y) + fabs((double)v.z) + fabs((double)v.w);
    }
    for (int o = 32; o; o >>= 1) { s += __shfl_down(s, o); a += __shfl_down(a, o); }
    if ((t & 63) == 0) { ls[t >> 6] = s; la[t >> 6] = a; }
    __syncthreads();
    if (t == 0) {
        for (int i = 1; i < 4; i++) { s += ls[i]; a += la[i]; }
        if (divn > 0) { dst->x = s / divn; dst->y = a / divn; }
        else          { dst->x = s;        dst->y = a; }
    }
}

// grid = 40 blocks: 0:c1 1:c1b 2:c2 3:fcl | 4-7:fc1/4 | 8-23:fc2/16 | 24-39:fc3/16
__global__ __launch_bounds__(256) void wstats_part(
    const float* __restrict__ a0, const float* __restrict__ a1,
    const float* __restrict__ a2, const float* __restrict__ a3,
    const float* __restrict__ a4, const float* __restrict__ a5,
    const float* __restrict__ a6, double2* __restrict__ part,
    double2* __restrict__ stats) {
    int b = blockIdx.x;
    if      (b == 0) bstat(a0, 144,   stats + 0, 144);
    else if (b == 1) bstat(a1, 144,   stats + 1, 144);
    else if (b == 2) bstat(a2, 13824, stats + 2, 13824);
    else if (b == 3) bstat(a6, 5120,  stats + 6, 5120);
    else if (b < 8)  bstat(a3 + (b - 4)  * 12288, 12288, part + (b - 4), 0);
    else if (b < 24) bstat(a4 + (b - 8)  * 16384, 16384, part + 4 + (b - 8), 0);
    else             bstat(a5 + (b - 24) * 16384, 16384, part + 20 + (b - 24), 0);
}

__global__ __launch_bounds__(64) void wstats_comb(const double2* __restrict__ part,
                                                  double2* __restrict__ stats) {
    int t = threadIdx.x;
    if (t == 0) {
        double s = 0, a = 0;
        for (int i = 0; i < 4; i++) { s += part[i].x; a += part[i].y; }
        stats[3].x = s / 49152.0; stats[3].y = a / 49152.0;
    } else if (t == 1) {
        double s = 0, a = 0;
        for (int i = 4; i < 20; i++) { s += part[i].x; a += part[i].y; }
        stats[4].x = s / 262144.0; stats[4].y = a / 262144.0;
    } else if (t == 2) {
        double s = 0, a = 0;
        for (int i = 20; i < 36; i++) { s += part[i].x; a += part[i].y; }
        stats[5].x = s / 262144.0; stats[5].y = a / 262144.0;
    }
}

// ============ conv weights -> ODD integer levels (as f32 ints) ============
__device__ inline float q4odd(float w, double mag) {
    double sc = 2.0 / fmax(mag, EPSQ);
    double q = fmin(fmax(rint((double)w * sc - 0.5), -8.0), 7.0);
    return (float)(2.0 * q + 1.0);
}

__global__ __launch_bounds__(256) void wq_conv(
    const float* __restrict__ wc1, const float* __restrict__ wc1b,
    const float* __restrict__ wc2, const double2* __restrict__ stats,
    float* __restrict__ c1o, float* __restrict__ c1bo, float* __restrict__ c2o) {
    int i = blockIdx.x * 256 + threadIdx.x;
    if (i < 144) c1o[i] = q4odd(wc1[i], stats[0].y);
    else if (i < 288) c1bo[i - 144] = q4odd(wc1b[i - 144], stats[1].y);
    else if (i < 288 + 13824) { int j = i - 288; c2o[j] = q4odd(wc2[j], stats[2].y); }
}

// ============ fc weights: binary sign {-1,0,1} as int8 (f64 mean) ============
__device__ inline char bsign(float w, double mean) {
    double d = (double)w - mean;
    return d > 0.0 ? (char)1 : (d < 0.0 ? (char)-1 : (char)0);
}

__global__ __launch_bounds__(256) void wq_fc(
    const float* __restrict__ wfc1, const float* __restrict__ wfc2,
    const float* __restrict__ wfc3, const float* __restrict__ wfcl,
    const double2* __restrict__ stats,
    char* __restrict__ f1, char* __restrict__ f2,
    char* __restrict__ f3, char* __restrict__ fl) {
    int i = blockIdx.x * 256 + threadIdx.x;
    if (i < 65536) {                       // f1: [512][128] padded, K=96
        int row = i >> 7, k = i & 127;
        f1[i] = (k < 96) ? bsign(wfc1[row * 96 + k], stats[3].x) : (char)0;
        return;
    }
    i -= 65536;
    if (i < 262144) { f2[i] = bsign(wfc2[i], stats[4].x); return; }
    i -= 262144;
    if (i < 262144) { f3[i] = bsign(wfc3[i], stats[5].x); return; }
    i -= 262144;
    if (i < 5120)   { fl[i] = bsign(wfcl[i], stats[6].x); }
}

// ============ exact integer 3-row pixel dot, f64 scale combine ============
template <int Wd>
__device__ inline double cpix(const float (&rq)[3][Wd], const float* wv,
                              const double* inv, int qx) {
    // products <= 127*15, sums <= 5715 < 2^24  -> fp32 arithmetic is EXACT
    float d0 = rq[0][qx] * wv[0] + rq[0][qx + 1] * wv[1] + rq[0][qx + 2] * wv[2];
    float d1 = rq[1][qx] * wv[3] + rq[1][qx + 1] * wv[4] + rq[1][qx + 2] * wv[5];
    float d2 = rq[2][qx] * wv[6] + rq[2][qx + 1] * wv[7] + rq[2][qx + 2] * wv[8];
    return (double)d0 * inv[0] + (double)d1 * inv[1] + (double)d2 * inv[2];
}

// ================= fused conv stack: one block per image =================
// v4: cw folded into per-row inv scales (f64 reassoc, ~1e-16 perturbation);
// all clamps dropped where post-relu values provably lie in [0,127].
__global__ __launch_bounds__(256) void conv_fused(
    const float* __restrict__ x, const float* __restrict__ w1o,
    const float* __restrict__ w1bo, const float* __restrict__ w2o,
    const double2* __restrict__ stats,
    char* __restrict__ xq96, double* __restrict__ arow) {
    __shared__ float sxp[16][17];
    __shared__ double sinv0[16];
    __shared__ float sh1[16][14][15];
    __shared__ double sinv1[16][14];
    __shared__ float sh2[16][12][13];
    __shared__ double sinv2[16][12];
    __shared__ float sw1[144], sw1b[144];
    __shared__ double sh3p[2][96];
    __shared__ double sh3[96];
    __shared__ double srs[2];
    int b = blockIdx.x, t = threadIdx.x;
    double cw1  = fmax(stats[0].y, EPSQ) * 0.25;
    double cw1b = fmax(stats[1].y, EPSQ) * 0.25;
    double cw2  = fmax(stats[2].y, EPSQ) * 0.25;

    // --- load + act_quant input (per row of 16); |v*s0| <= 127 -> no clamps ---
    float v = x[(size_t)b * 256 + t];
    if (t < 144) { sw1[t] = w1o[t]; sw1b[t] = w1bo[t]; }
    float m = fabsf(v);
    for (int o = 8; o; o >>= 1) m = fmaxf(m, __shfl_xor(m, o));
    double s0 = 127.0 / fmax((double)m, EPSQ);
    sxp[t >> 4][t & 15] = (float)rint((double)v * s0);
    if ((t & 15) == 0) sinv0[t >> 4] = 1.0 / s0;
    __syncthreads();

    // --- conv1 3x3, 1->16ch, relu, act_quant rows of 14 ---
    if (t < 224) {
        int c = t / 14, r = t % 14;
        float rq[3][16]; double inv[3];
        #pragma unroll
        for (int i = 0; i < 3; i++) {
            inv[i] = sinv0[r + i] * cw1;      // fold cw1 (safe f64 reassoc)
            #pragma unroll
            for (int j = 0; j < 16; j++) rq[i][j] = sxp[r + i][j];
        }
        float wv[9];
        #pragma unroll
        for (int k = 0; k < 9; k++) wv[k] = sw1[c * 9 + k];
        double vals[14]; double mx = 0.0;
        #pragma unroll
        for (int qx = 0; qx < 14; qx++) {
            vals[qx] = fmax(cpix(rq, wv, inv, qx), 0.0);
            mx = fmax(mx, vals[qx]);
        }
        double s2 = 127.0 / fmax(mx, EPSQ);
        sinv1[c][r] = 1.0 / s2;
        #pragma unroll
        for (int qx = 0; qx < 14; qx++)
            sh1[c][r][qx] = (float)rint(vals[qx] * s2);   // in [0,127]
    }
    __syncthreads();

    // --- depthwise 3x3, relu, act_quant rows of 12 ---
    if (t < 192) {
        int c = t / 12, r = t % 12;
        float rq[3][14]; double inv[3];
        #pragma unroll
        for (int i = 0; i < 3; i++) {
            inv[i] = sinv1[c][r + i] * cw1b;
            #pragma unroll
            for (int j = 0; j < 14; j++) rq[i][j] = sh1[c][r + i][j];
        }
        float wv[9];
        #pragma unroll
        for (int k = 0; k < 9; k++) wv[k] = sw1b[c * 9 + k];
        double vals[12]; double mx = 0.0;
        #pragma unroll
        for (int qx = 0; qx < 12; qx++) {
            vals[qx] = fmax(cpix(rq, wv, inv, qx), 0.0);
            mx = fmax(mx, vals[qx]);
        }
        double s3 = 127.0 / fmax(mx, EPSQ);
        sinv2[c][r] = 1.0 / s3;
        #pragma unroll
        for (int qx = 0; qx < 12; qx++)
            sh2[c][r][qx] = (float)rint(vals[qx] * s3);
    }
    __syncthreads();

    // --- grouped conv2: 192 threads, 2 half-partials per output ---
    if (t < 192) {
        int o = t % 96, half = t / 96;
        int g = o / 6;
        const float* wk = w2o + o * 144 + half * 72;
        double acc = 0.0;
        #pragma unroll
        for (int hh = 0; hh < 6; hh++) {
            int row = half * 6 + hh;
            float4 w0 = *(const float4*)(wk + hh * 12);
            float4 w1 = *(const float4*)(wk + hh * 12 + 4);
            float4 w2v = *(const float4*)(wk + hh * 12 + 8);
            const float* sr = &sh2[g][row][0];
            float d = 0.f;
            d += sr[0] * w0.x; d += sr[1] * w0.y; d += sr[2] * w0.z; d += sr[3] * w0.w;
            d += sr[4] * w1.x; d += sr[5] * w1.y; d += sr[6] * w1.z; d += sr[7] * w1.w;
            d += sr[8] * w2v.x; d += sr[9] * w2v.y; d += sr[10] * w2v.z; d += sr[11] * w2v.w;
            acc += (double)d * sinv2[g][row];
        }
        sh3p[half][o] = acc;
    }
    __syncthreads();
    if (t < 96) sh3[t] = fmax((sh3p[0][t] + sh3p[1][t]) * cw2, 0.0);
    __syncthreads();

    // --- rmsnorm + act_quant over 96, f64 ---
    if (t < 64) {
        double a = sh3[t];
        double bb = (t < 32) ? sh3[64 + t] : 0.0;
        double ss = a * a + bb * bb;
        double mxx = fmax(fabs(a), fabs(bb));
        for (int o = 32; o; o >>= 1) {
            ss += __shfl_down(ss, o);
            mxx = fmax(mxx, __shfl_down(mxx, o));
        }
        if (t == 0) {
            double r = 1.0 / sqrt(ss / 96.0 + 1e-5);
            double s4 = 127.0 / fmax(mxx * r, EPSQ);
            srs[0] = r; srs[1] = s4;
        }
    }
    __syncthreads();
    if (t < 128) {
        char q = 0;
        if (t < 96) {
            double xn = sh3[t] * srs[0];
            q = (char)(int)rint(xn * srs[1]);   // in [0,127]
        }
        xq96[(size_t)b * 128 + t] = q;
        if (t == 0) arow[b] = 1.0 / srs[1];
    }
}

// ======= fused FC layer: xq_out = act_quant(rmsnorm(relu(Xq·Wq^T))) =======
// BM=32 rows, BN=512 (full), BK=128. 4 waves; wave w owns cols [w*128,+128).
// int32 MFMA exact; relu exact; rmsnorm stats in f64 (reassoc-safe);
// writes int8 output + updates arow in place (row-disjoint blocks).
__global__ __launch_bounds__(256, 2) void fc_fused(
    const char* __restrict__ Xq, const char* __restrict__ Wq, int K,
    const double2* __restrict__ stats, int sidx,
    double* __restrict__ arow, char* __restrict__ xq) {
    __shared__ char As[32 * 128];
    __shared__ char Bs[512 * 128];
    __shared__ double redS[4][32];
    __shared__ int    redM[4][32];
    __shared__ double csrow[32];
    int t = threadIdx.x;
    int lane = t & 63;
    int w = t >> 6;
    int m0 = blockIdx.x * 32;

    v16i acc[4] = {};

    for (int k0 = 0; k0 < K; k0 += 128) {
        // stage A (32x128) and B (512x128), XOR-swizzled rows
        {
            int row = t >> 3, cb = (t & 7) * 16;
            *(int4*)(As + row * 128 + (cb ^ ((row & 7) << 4))) =
                *(const int4*)(Xq + (size_t)(m0 + row) * K + k0 + cb);
        }
        #pragma unroll
        for (int p = 0; p < 16; p++) {
            int slot = p * 256 + t;
            int row = slot >> 3, cb = (slot & 7) * 16;
            *(int4*)(Bs + row * 128 + (cb ^ ((row & 7) << 4))) =
                *(const int4*)(Wq + (size_t)row * K + k0 + cb);
        }
        __syncthreads();
        int ra = lane & 31;
        int ksel = (lane >> 5) * 16;
        #pragma unroll
        for (int kk = 0; kk < 4; kk++) {
            int kb = kk * 32 + ksel;
            v4i a = *(v4i*)(As + ra * 128 + (kb ^ ((ra & 7) << 4)));
            #pragma unroll
            for (int nt = 0; nt < 4; nt++) {
                int rb = w * 128 + nt * 32 + (lane & 31);
                v4i bb = *(v4i*)(Bs + rb * 128 + (kb ^ ((rb & 7) << 4)));
                acc[nt] = __builtin_amdgcn_mfma_i32_32x32x32_i8(a, bb, acc[nt], 0, 0, 0);
            }
        }
        __syncthreads();
    }

    // --- relu (exact) + per-row sumsq (f64) and max (int), butterfly over 32 lanes ---
    double ps[16]; int pm[16];
    #pragma unroll
    for (int reg = 0; reg < 16; reg++) {
        int v0 = max(acc[0][reg], 0), v1 = max(acc[1][reg], 0);
        int v2 = max(acc[2][reg], 0), v3 = max(acc[3][reg], 0);
        acc[0][reg] = v0; acc[1][reg] = v1; acc[2][reg] = v2; acc[3][reg] = v3;
        ps[reg] = (double)v0 * v0 + (double)v1 * v1 + (double)v2 * v2 + (double)v3 * v3;
        pm[reg] = max(max(v0, v1), max(v2, v3));
    }
    #pragma unroll
    for (int o = 1; o < 32; o <<= 1) {
        #pragma unroll
        for (int reg = 0; reg < 16; reg++) {
            ps[reg] += __shfl_xor(ps[reg], o);
            pm[reg] = max(pm[reg], __shfl_xor(pm[reg], o));
        }
    }
    if ((lane & 31) == 0) {
        int h = lane >> 5;
        #pragma unroll
        for (int reg = 0; reg < 16; reg++) {
            int row = (reg & 3) + 8 * (reg >> 2) + 4 * h;
            redS[w][row] = ps[reg];
            redM[w][row] = pm[reg];
        }
    }
    __syncthreads();
    if (t < 32) {
        double S = redS[0][t] + redS[1][t] + redS[2][t] + redS[3][t];
        int M = max(max(redM[0][t], redM[1][t]), max(redM[2][t], redM[3][t]));
        double c = stats[sidx].y * arow[m0 + t];
        double mean = S * c * c / 512.0;
        double r = 1.0 / sqrt(mean + 1e-5);
        double s = 127.0 / fmax((double)M * c * r, EPSQ);
        csrow[t] = c * r * s;
        arow[m0 + t] = 1.0 / s;
    }
    __syncthreads();

    // --- quantize (values in [0,127]) into Bs as [32][512] bytes, then copy out ---
    #pragma unroll
    for (int nt = 0; nt < 4; nt++) {
        int col = w * 128 + nt * 32 + (lane & 31);
        #pragma unroll
        for (int reg = 0; reg < 16; reg++) {
            int row = (reg & 3) + 8 * (reg >> 2) + 4 * (lane >> 5);
            Bs[row * 512 + col] = (char)(int)rint((double)acc[nt][reg] * csrow[row]);
        }
    }
    __syncthreads();
    #pragma unroll
    for (int i = 0; i < 4; i++) {
        int idx = i * 256 + t;
        *(int4*)(xq + (size_t)m0 * 512 + idx * 16) = *(const int4*)(Bs + idx * 16);
    }
}

// ================= final layer: N=10, exact int dot =================
__device__ inline int bdot(int a, int b) {
    int r = ((a << 24) >> 24) * ((b << 24) >> 24);
    r += ((a << 16) >> 24) * ((b << 16) >> 24);
    r += ((a << 8) >> 24) * ((b << 8) >> 24);
    r += (a >> 24) * (b >> 24);
    return r;
}

__global__ __launch_bounds__(256) void fcl_k(const char* __restrict__ Xq,
                                             const char* __restrict__ Wq,
                                             const double* __restrict__ arow,
                                             const double2* __restrict__ stats,
                                             float* __restrict__ out) {
    int gi = blockIdx.x * 256 + threadIdx.x;     // 163840 = 16384*10 exact
    int mrow = gi / 10, n = gi - mrow * 10;
    const int4* xp = (const int4*)(Xq + (size_t)mrow * 512);
    const int4* wp = (const int4*)(Wq + n * 512);
    int acc = 0;
    #pragma unroll 8
    for (int i = 0; i < 32; i++) {
        int4 a = xp[i], b = wp[i];
        acc += bdot(a.x, b.x) + bdot(a.y, b.y) + bdot(a.z, b.z) + bdot(a.w, b.w);
    }
    out[gi] = (float)((double)acc * stats[6].y * arow[mrow]);
}

// ================= launcher =================
extern "C" void kernel_launch(void* const* d_in, const int* in_sizes, int n_in,
                              void* d_out, int out_size, void* d_ws, size_t ws_size,
                              hipStream_t stream) {
    const float* x     = (const float*)d_in[0];
    const float* w_c1  = (const float*)d_in[1];
    const float* w_c1b = (const float*)d_in[2];
    const float* w_c2  = (const float*)d_in[3];
    const float* w_fc1 = (const float*)d_in[4];
    const float* w_fc2 = (const float*)d_in[5];
    const float* w_fc3 = (const float*)d_in[6];
    const float* w_fcl = (const float*)d_in[7];
    float* out = (float*)d_out;
    char* wsb = (char*)d_ws;
    const int B = 16384;

    // ws layout (byte offsets, 16B-aligned)
    float*   c1o   = (float*)(wsb + 0);          // 576 B
    float*   c1bo  = (float*)(wsb + 1024);       // 576 B
    float*   c2o   = (float*)(wsb + 2048);       // 55296 B
    double2* stats = (double2*)(wsb + 57344);    // 112 B
    double2* part  = (double2*)(wsb + 57856);    // 576 B
    char*    f1q   = wsb + 65536;                // 512*128
    char*    f2q   = wsb + 131072;               // 512*512
    char*    f3q   = wsb + 393216;               // 512*512
    char*    flq   = wsb + 655360;               // 10*512
    double*  arow  = (double*)(wsb + 663552);    // B doubles
    char*    xq96  = wsb + 1048576;              // B*128
    char*    xq512 = wsb + 3145728;              // B*512 (end ~11.5 MB)

    // --- weight stats + quantization ---
    wstats_part<<<40, 256, 0, stream>>>(w_c1, w_c1b, w_c2, w_fc1, w_fc2, w_fc3,
                                        w_fcl, part, stats);
    wstats_comb<<<1, 64, 0, stream>>>(part, stats);
    wq_conv<<<56, 256, 0, stream>>>(w_c1, w_c1b, w_c2, stats, c1o, c1bo, c2o);
    wq_fc<<<2324, 256, 0, stream>>>(w_fc1, w_fc2, w_fc3, w_fcl, stats, f1q, f2q, f3q, flq);

    // --- conv stack -> int8 [B,128] + f64 arow ---
    conv_fused<<<B, 256, 0, stream>>>(x, c1o, c1bo, c2o, stats, xq96, arow);

    // --- fused FC layers (gemm + relu + rmsnorm + act_quant each) ---
    fc_fused<<<B / 32, 256, 0, stream>>>(xq96,  f1q, 128, stats, 3, arow, xq512);
    fc_fused<<<B / 32, 256, 0, stream>>>(xq512, f2q, 512, stats, 4, arow, xq512);
    fc_fused<<<B / 32, 256, 0, stream>>>(xq512, f3q, 512, stats, 5, arow, xq512);

    // --- fcl ---
    fcl_k<<<640, 256, 0, stream>>>(xq512, flq, arow, stats, out);
}